// Round 8
// baseline (140.531 us; speedup 1.0000x reference)
//
#include <hip/hip_runtime.h>
#include <math.h>

#define H 8
#define K 4
#define NN 4
#define D 256
#define NQ 1024
#define NKV 2048
#define BATCH 2
#define CH 32           // D / H
#define GC 16           // grid cells per axis
#define CELLH 0.0625f   // 1/16

// workspace layout (bytes)
#define OFF_LOC   0u          // 65536 * float2 = 512 KB
#define OFF_ATTN  524288u     // 65536 * f32    = 256 KB
#define OFF_VWS   786432u     // 16*2048*32 f32 = 4 MB
#define OFF_HEAD  4980736u    // 2*1024*256 f32 = 2 MB
#define OFF_PTS   7077888u    // 2*2048 float4  = 64 KB (cell-sorted)
#define OFF_CST   7143424u    // 2*257 i32 cell starts (+pad)
#define WS_NEED   7147520u

// ---------------------------------------------------------------------------
// Kernel 1: off = q@W_off + b_off (sequential fmaf chain = Eigen/oneDNN sgemm
// semantics, bias after) -> loc; attn = softmax_K(q@W_attn + b_attn)
// ---------------------------------------------------------------------------
__global__ void k_offattn(const float* __restrict__ q, const float* __restrict__ qpos,
                          const float* __restrict__ Woff, const float* __restrict__ boff,
                          const float* __restrict__ Wattn, const float* __restrict__ battn,
                          float* __restrict__ loc, float* __restrict__ attnw) {
    int row = blockIdx.x;            // b*NQ + q
    int b = row >> 10, qi = row & (NQ - 1);
    __shared__ float qs[D];
    for (int d = threadIdx.x; d < D; d += blockDim.x) qs[d] = q[(size_t)row * D + d];
    __syncthreads();
    int j = threadIdx.x;
    if (j < 64) {
        float acc = 0.0f;
        for (int d = 0; d < D; ++d) acc = fmaf(qs[d], Woff[d * 64 + j], acc);
        float off = acc + boff[j];               // bias after, like np
        int xy = j & 1;
        int hk = j >> 1;                         // h*4 + k
        int h = hk >> 2, k = hk & 3;
        float L = qpos[(size_t)row * 2 + xy] + off;
        int g = ((b * H + h) * NQ + qi) * K + k;
        loc[(size_t)g * 2 + xy] = L;
    } else if (j < 96) {
        int j2 = j - 64;                         // h*4 + k
        float acc = 0.0f;
        for (int d = 0; d < D; ++d) acc = fmaf(qs[d], Wattn[d * 32 + j2], acc);
        acc += battn[j2];
        float m = acc;
        m = fmaxf(m, __shfl_xor(m, 1));
        m = fmaxf(m, __shfl_xor(m, 2));
        float e = expf(acc - m);
        float s = e;
        s += __shfl_xor(s, 1);
        s += __shfl_xor(s, 2);
        float w = e / s;
        int h = j2 >> 2, k = j2 & 3;
        attnw[((b * H + h) * NQ + qi) * K + k] = w;
    }
}

// ---------------------------------------------------------------------------
// Kernel 2: values = kv @ W_v + b_v, stored transposed as [b*H][n_kv][32] f32.
// ---------------------------------------------------------------------------
__global__ void k_values(const float* __restrict__ kv, const float* __restrict__ Wv,
                         const float* __restrict__ bv, float* __restrict__ vws) {
    int r0 = blockIdx.x * 4;         // row = b*NKV + n
    __shared__ float ks[4][D];
    for (int t = threadIdx.x; t < 4 * D; t += 256) ks[t >> 8][t & 255] = kv[(size_t)r0 * D + t];
    __syncthreads();
    int c = threadIdx.x;             // h*32 + cc
    float a0 = 0.f, a1 = 0.f, a2 = 0.f, a3 = 0.f;
    for (int d = 0; d < D; ++d) {
        float w = Wv[d * D + c];
        a0 = fmaf(ks[0][d], w, a0); a1 = fmaf(ks[1][d], w, a1);
        a2 = fmaf(ks[2][d], w, a2); a3 = fmaf(ks[3][d], w, a3);
    }
    float bias = bv[c];
    a0 += bias; a1 += bias; a2 += bias; a3 += bias;
    int h = c >> 5, cc = c & 31;
    float va[4] = {a0, a1, a2, a3};
    for (int r = 0; r < 4; ++r) {
        int row = r0 + r;
        int b = row >> 11, n = row & (NKV - 1);
        vws[(((size_t)(b * H + h) * NKV) + n) * CH + cc] = va[r];
    }
}

// ---------------------------------------------------------------------------
// Kernel B: bin kv points into 16x16 cells (per batch), cell-sorted float4
// (-2x, -2y, x^2+y^2, (float)origIdx) + cellStart[257].
// ---------------------------------------------------------------------------
__global__ void k_bin(const float* __restrict__ kvpos, float4* __restrict__ pts4,
                      int* __restrict__ cellStart) {
    #pragma clang fp contract(off)
    int b = blockIdx.x;
    int tid = threadIdx.x;
    __shared__ int cnt[GC * GC];
    __shared__ int ofs[GC * GC + 1];
    __shared__ int cur[GC * GC];
    if (tid < GC * GC) cnt[tid] = 0;
    __syncthreads();
    for (int n = tid; n < NKV; n += 256) {
        float x = kvpos[(size_t)(b * NKV + n) * 2 + 0];
        float y = kvpos[(size_t)(b * NKV + n) * 2 + 1];
        int ix = min(GC - 1, max(0, (int)floorf(x * (float)GC)));
        int iy = min(GC - 1, max(0, (int)floorf(y * (float)GC)));
        atomicAdd(&cnt[iy * GC + ix], 1);
    }
    __syncthreads();
    if (tid == 0) {
        int s = 0;
        for (int c = 0; c < GC * GC; ++c) { ofs[c] = s; s += cnt[c]; }
        ofs[GC * GC] = s;
    }
    __syncthreads();
    for (int t = tid; t < GC * GC + 1; t += 256) cellStart[b * 257 + t] = ofs[t];
    if (tid < GC * GC) cur[tid] = ofs[tid];
    __syncthreads();
    for (int n = tid; n < NKV; n += 256) {
        float x = kvpos[(size_t)(b * NKV + n) * 2 + 0];
        float y = kvpos[(size_t)(b * NKV + n) * 2 + 1];
        int ix = min(GC - 1, max(0, (int)floorf(x * (float)GC)));
        int iy = min(GC - 1, max(0, (int)floorf(y * (float)GC)));
        int pos = atomicAdd(&cur[iy * GC + ix], 1);
        pts4[(size_t)b * NKV + pos] = make_float4(-2.0f * x, -2.0f * y, x * x + y * y, (float)n);
    }
}

// ---------------------------------------------------------------------------
// Branchless lexicographic (d, idx) stable top-4 insert (scan path: candidate
// sets are disjoint, no dup possible).
// ---------------------------------------------------------------------------
__device__ __forceinline__ void lexins(float t, int n,
                                       float& d0, float& d1, float& d2, float& d3,
                                       int& i0, int& i1, int& i2, int& i3) {
    bool c0 = (t < d0) || (t == d0 && n < i0);
    bool c1 = (t < d1) || (t == d1 && n < i1);
    bool c2 = (t < d2) || (t == d2 && n < i2);
    bool c3 = (t < d3) || (t == d3 && n < i3);
    d3 = c3 ? (c2 ? d2 : t) : d3;   i3 = c3 ? (c2 ? i2 : n) : i3;
    d2 = c2 ? (c1 ? d1 : t) : d2;   i2 = c2 ? (c1 ? i1 : n) : i2;
    d1 = c1 ? (c0 ? d0 : t) : d1;   i1 = c1 ? (c0 ? i0 : n) : i1;
    d0 = c0 ? t : d0;               i0 = c0 ? n : i0;
}

// DEDUP variant for merging lists that may share entries (repeated butterfly
// merges across ring iterations): an index already present is never
// re-inserted.
__device__ __forceinline__ void lexins_d(float t, int n,
                                         float& d0, float& d1, float& d2, float& d3,
                                         int& i0, int& i1, int& i2, int& i3) {
    bool nd = !((n == i0) | (n == i1) | (n == i2) | (n == i3));
    bool c0 = nd && ((t < d0) || (t == d0 && n < i0));
    bool c1 = nd && ((t < d1) || (t == d1 && n < i1));
    bool c2 = nd && ((t < d2) || (t == d2 && n < i2));
    bool c3 = nd && ((t < d3) || (t == d3 && n < i3));
    d3 = c3 ? (c2 ? d2 : t) : d3;   i3 = c3 ? (c2 ? i2 : n) : i3;
    d2 = c2 ? (c1 ? d1 : t) : d2;   i2 = c2 ? (c1 ? i1 : n) : i2;
    d1 = c1 ? (c0 ? d0 : t) : d1;   i1 = c1 ? (c0 ? i0 : n) : i1;
    d0 = c0 ? t : d0;               i0 = c0 ? n : i0;
}

// strict-< variant for the ascending-order brute-force fallback
__device__ __forceinline__ void bins4(float t, int n,
                                      float& d0, float& d1, float& d2, float& d3,
                                      int& i0, int& i1, int& i2, int& i3) {
    bool c0 = t < d0, c1 = t < d1, c2 = t < d2, c3 = t < d3;
    d3 = c3 ? (c2 ? d2 : t) : d3;   i3 = c3 ? (c2 ? i2 : n) : i3;
    d2 = c2 ? (c1 ? d1 : t) : d2;   i2 = c2 ? (c1 ? i1 : n) : i2;
    d1 = c1 ? (c0 ? d0 : t) : d1;   i1 = c1 ? (c0 ? i0 : n) : i1;
    d0 = c0 ? t : d0;               i0 = c0 ? n : i0;
}

// ---------------------------------------------------------------------------
// Shepard weights + gather + weighted sum + head write (fallback tail).
// ---------------------------------------------------------------------------
__device__ __forceinline__ void knn_tail(int g, float lx, float ly,
                                         int i0, int i1, int i2, int i3,
                                         const float* __restrict__ kvpos,
                                         const float* __restrict__ attnw,
                                         const float* __restrict__ vws,
                                         float power, float* __restrict__ head) {
    #pragma clang fp contract(off)
    int bh = g >> 12;
    int b = bh >> 3, h = bh & 7;
    int qi = (g >> 2) & (NQ - 1);
    int k = g & 3;
    int idx[4] = {i0, i1, i2, i3};
    float z[4];
    #pragma unroll
    for (int u = 0; u < 4; ++u) {
        float kx = kvpos[(size_t)(b * NKV + idx[u]) * 2 + 0];
        float ky = kvpos[(size_t)(b * NKV + idx[u]) * 2 + 1];
        float dx = kx - lx;
        float dy = ky - ly;
        float dist = sqrtf(dx * dx + dy * dy) + 1e-6f;
        z[u] = -power * dist;
    }
    float m = fmaxf(fmaxf(z[0], z[1]), fmaxf(z[2], z[3]));
    float e0 = expf(z[0] - m), e1 = expf(z[1] - m), e2 = expf(z[2] - m), e3 = expf(z[3] - m);
    float esum = e0 + e1 + e2 + e3;
    float w0 = e0 / esum, w1 = e1 / esum, w2 = e2 / esum, w3 = e3 / esum;

    const float4* vp0 = (const float4*)(vws + ((size_t)bh * NKV + i0) * CH);
    const float4* vp1 = (const float4*)(vws + ((size_t)bh * NKV + i1) * CH);
    const float4* vp2 = (const float4*)(vws + ((size_t)bh * NKV + i2) * CH);
    const float4* vp3 = (const float4*)(vws + ((size_t)bh * NKV + i3) * CH);
    float a = attnw[g];
    float4 acc[8];
    #pragma unroll
    for (int t = 0; t < 8; ++t) {
        float4 x0 = vp0[t], x1 = vp1[t], x2 = vp2[t], x3 = vp3[t];
        float4 r;
        r.x = a * (w0 * x0.x + w1 * x1.x + w2 * x2.x + w3 * x3.x);
        r.y = a * (w0 * x0.y + w1 * x1.y + w2 * x2.y + w3 * x3.y);
        r.z = a * (w0 * x0.z + w1 * x1.z + w2 * x2.z + w3 * x3.z);
        r.w = a * (w0 * x0.w + w1 * x1.w + w2 * x2.w + w3 * x3.w);
        r.x += __shfl_xor(r.x, 1); r.x += __shfl_xor(r.x, 2);
        r.y += __shfl_xor(r.y, 1); r.y += __shfl_xor(r.y, 2);
        r.z += __shfl_xor(r.z, 1); r.z += __shfl_xor(r.z, 2);
        r.w += __shfl_xor(r.w, 1); r.w += __shfl_xor(r.w, 2);
        acc[t] = r;
    }
    float4* hp = (float4*)(head + ((size_t)(b * NQ + qi)) * D + h * CH);
    hp[k * 2]     = acc[k * 2];
    hp[k * 2 + 1] = acc[k * 2 + 1];
}

// ---------------------------------------------------------------------------
// Kernel 3: grid-accelerated exact 4-NN, 4 LANES PER POINT, GLOBAL gather.
// pts4 (64 KB total) is L1/L2-resident — no LDS staging, so LDS = 1 KB and
// residency is thread-limited (8 blocks/CU = 32 waves/CU) instead of
// LDS-limited (~1 block/CU).  Selection logic identical to round 7.
// ---------------------------------------------------------------------------
__global__ void k_knn_grid2(const float* __restrict__ kvpos, const float* __restrict__ loc,
                            const float* __restrict__ attnw, const float* __restrict__ vws,
                            const float* __restrict__ sp,
                            const float4* __restrict__ pts4, const int* __restrict__ cellStart,
                            float* __restrict__ head) {
    #pragma clang fp contract(off)
    int lane = threadIdx.x;
    int s = lane & 3;
    int g = blockIdx.x * 64 + (lane >> 2);    // point id
    int b = g >> 15;
    int bh = g >> 12;

    __shared__ int cst[GC * GC + 1];
    for (int i = threadIdx.x; i < GC * GC + 1; i += 256) cst[i] = cellStart[b * 257 + i];
    __syncthreads();

    const float4* gp = pts4 + (size_t)b * NKV;

    const float2* lp = (const float2*)loc;
    float2 L = lp[g];
    float lx = L.x, ly = L.y;
    float sl = lx * lx + ly * ly;

    int ix = min(GC - 1, max(0, (int)floorf(lx * (float)GC)));
    int iy = min(GC - 1, max(0, (int)floorf(ly * (float)GC)));

    float d0 = 1e30f, d1 = 1e30f, d2 = 1e30f, d3 = 1e30f;
    int i0 = 0x7FFFFFFF, i1 = 0x7FFFFFFF, i2 = 0x7FFFFFFF, i3 = 0x7FFFFFFF;

#define SCAN_RANGE_S(JLO, JHI)                                       \
    for (int j = (JLO) + s; j < (JHI); j += 4) {                     \
        float4 p = gp[j];                                            \
        float t = (sl + p.z) + fmaf(ly, p.y, lx * p.x);              \
        lexins(t, (int)p.w, d0, d1, d2, d3, i0, i1, i2, i3);         \
    }

#define MERGE_STEP(M) {                                                        \
        float e0 = __shfl_xor(d0, M), e1 = __shfl_xor(d1, M);                  \
        float e2 = __shfl_xor(d2, M), e3 = __shfl_xor(d3, M);                  \
        int j0 = __shfl_xor(i0, M), j1 = __shfl_xor(i1, M);                    \
        int j2 = __shfl_xor(i2, M), j3 = __shfl_xor(i3, M);                    \
        lexins_d(e0, j0, d0, d1, d2, d3, i0, i1, i2, i3);                      \
        lexins_d(e1, j1, d0, d1, d2, d3, i0, i1, i2, i3);                      \
        lexins_d(e2, j2, d0, d1, d2, d3, i0, i1, i2, i3);                      \
        lexins_d(e3, j3, d0, d1, d2, d3, i0, i1, i2, i3);                      \
    }

    // phase 1: clamped 3x3 box, each row a contiguous range, stride-4 by s
    {
        int bx0 = max(ix - 1, 0), bx1 = min(ix + 1, GC - 1);
        int by0 = max(iy - 1, 0), by1 = min(iy + 1, GC - 1);
        for (int cy = by0; cy <= by1; ++cy) {
            int base = cy * GC;
            SCAN_RANGE_S(cst[base + bx0], cst[base + bx1 + 1]);
        }
    }
    MERGE_STEP(1);
    MERGE_STEP(2);

    // done check for box radius r (post-merge: uniform across the 4-lane group)
    auto done_at = [&](int r) -> bool {
        int bx0 = ix - r, bx1 = ix + r, by0 = iy - r, by1 = iy + r;
        float bound = 1e30f;
        if (bx0 > 0)      bound = fminf(bound, lx - (float)bx0 * CELLH);
        if (bx1 < GC - 1) bound = fminf(bound, (float)(bx1 + 1) * CELLH - lx);
        if (by0 > 0)      bound = fminf(bound, ly - (float)by0 * CELLH);
        if (by1 < GC - 1) bound = fminf(bound, (float)(by1 + 1) * CELLH - ly);
        bool covered = (bx0 <= 0 && bx1 >= GC - 1 && by0 <= 0 && by1 >= GC - 1);
        return covered || (d3 < bound * bound - 1e-5f);
    };

    int r = 1;
    bool need = !done_at(1);
    while (__any(need)) {
        ++r;
        if (need) {
            int ry0 = iy - r, ry1 = iy + r;
            int rx0 = ix - r, rx1 = ix + r;
            int ca = max(rx0, 0), cb = min(rx1, GC - 1);
            if (ry0 >= 0)      { int base = ry0 * GC; SCAN_RANGE_S(cst[base + ca], cst[base + cb + 1]); }
            if (ry1 <= GC - 1) { int base = ry1 * GC; SCAN_RANGE_S(cst[base + ca], cst[base + cb + 1]); }
            int ya = max(ry0 + 1, 0), yb = min(ry1 - 1, GC - 1);
            if (rx0 >= 0)      for (int cy = ya; cy <= yb; ++cy) { int c = cy * GC + rx0; SCAN_RANGE_S(cst[c], cst[c + 1]); }
            if (rx1 <= GC - 1) for (int cy = ya; cy <= yb; ++cy) { int c = cy * GC + rx1; SCAN_RANGE_S(cst[c], cst[c + 1]); }
            MERGE_STEP(1);
            MERGE_STEP(2);
            need = !done_at(r);
        }
    }
#undef SCAN_RANGE_S
#undef MERGE_STEP

    // ---- tail, split 4-way over channel chunks ----
    int bb = bh >> 3, h = bh & 7;
    int qi = (g >> 2) & (NQ - 1);
    float power = fmaxf(sp[0], 0.0f) + 1e-6f;
    int idx[4] = {i0, i1, i2, i3};
    float z[4];
    #pragma unroll
    for (int u = 0; u < 4; ++u) {
        float kx = kvpos[(size_t)(bb * NKV + idx[u]) * 2 + 0];
        float ky = kvpos[(size_t)(bb * NKV + idx[u]) * 2 + 1];
        float dx = kx - lx;
        float dy = ky - ly;
        float dist = sqrtf(dx * dx + dy * dy) + 1e-6f;
        z[u] = -power * dist;
    }
    float m = fmaxf(fmaxf(z[0], z[1]), fmaxf(z[2], z[3]));
    float e0 = expf(z[0] - m), e1 = expf(z[1] - m), e2 = expf(z[2] - m), e3 = expf(z[3] - m);
    float esum = e0 + e1 + e2 + e3;
    float w0 = e0 / esum, w1 = e1 / esum, w2 = e2 / esum, w3 = e3 / esum;

    const float4* vp0 = (const float4*)(vws + ((size_t)bh * NKV + i0) * CH);
    const float4* vp1 = (const float4*)(vws + ((size_t)bh * NKV + i1) * CH);
    const float4* vp2 = (const float4*)(vws + ((size_t)bh * NKV + i2) * CH);
    const float4* vp3 = (const float4*)(vws + ((size_t)bh * NKV + i3) * CH);
    float a = attnw[g];
    float4* hp = (float4*)(head + ((size_t)(bb * NQ + qi)) * D + h * CH);
    #pragma unroll
    for (int u = 0; u < 2; ++u) {
        int t = s * 2 + u;
        float4 x0 = vp0[t], x1 = vp1[t], x2 = vp2[t], x3 = vp3[t];
        float4 rr;
        rr.x = a * (w0 * x0.x + w1 * x1.x + w2 * x2.x + w3 * x3.x);
        rr.y = a * (w0 * x0.y + w1 * x1.y + w2 * x2.y + w3 * x3.y);
        rr.z = a * (w0 * x0.z + w1 * x1.z + w2 * x2.z + w3 * x3.z);
        rr.w = a * (w0 * x0.w + w1 * x1.w + w2 * x2.w + w3 * x3.w);
        rr.x += __shfl_xor(rr.x, 4); rr.x += __shfl_xor(rr.x, 8);   // sum over k
        rr.y += __shfl_xor(rr.y, 4); rr.y += __shfl_xor(rr.y, 8);
        rr.z += __shfl_xor(rr.z, 4); rr.z += __shfl_xor(rr.z, 8);
        rr.w += __shfl_xor(rr.w, 4); rr.w += __shfl_xor(rr.w, 8);
        if (((lane >> 2) & 3) == 0) hp[t] = rr;                     // k==0 lanes write
    }
}

// Fallback (ws too small): brute-force fused scan (round-4 validated path)
__global__ void k_knn_fused(const float* __restrict__ kvpos, const float* __restrict__ loc,
                            const float* __restrict__ attnw, const float* __restrict__ vws,
                            const float* __restrict__ sp, float* __restrict__ head) {
    #pragma clang fp contract(off)
    int g = blockIdx.x * 256 + threadIdx.x;
    int bh = g >> 12;
    int b = bh >> 3;
    __shared__ float sx[NKV];
    __shared__ float sy[NKV];
    __shared__ float sz[NKV];
    for (int n = threadIdx.x; n < NKV; n += 256) {
        float x = kvpos[(size_t)(b * NKV + n) * 2 + 0];
        float y = kvpos[(size_t)(b * NKV + n) * 2 + 1];
        sx[n] = -2.0f * x;
        sy[n] = -2.0f * y;
        sz[n] = x * x + y * y;
    }
    __syncthreads();
    const float2* lp = (const float2*)loc;
    float2 L = lp[g];
    float lx = L.x, ly = L.y;
    float sl = lx * lx + ly * ly;
    const float4* x4 = (const float4*)sx;
    const float4* y4 = (const float4*)sy;
    const float4* z4 = (const float4*)sz;
    float d0 = 1e30f, d1 = 1e30f, d2 = 1e30f, d3 = 1e30f;
    int i0 = 0, i1 = 0, i2 = 0, i3 = 0;
    for (int n = 0; n < NKV; n += 4) {
        int v = n >> 2;
        float4 xA = x4[v], yA = y4[v], zA = z4[v];
        float t0 = (sl + zA.x) + fmaf(ly, yA.x, lx * xA.x);
        float t1 = (sl + zA.y) + fmaf(ly, yA.y, lx * xA.y);
        float t2 = (sl + zA.z) + fmaf(ly, yA.z, lx * xA.z);
        float t3 = (sl + zA.w) + fmaf(ly, yA.w, lx * xA.w);
        bins4(t0, n + 0, d0, d1, d2, d3, i0, i1, i2, i3);
        bins4(t1, n + 1, d0, d1, d2, d3, i0, i1, i2, i3);
        bins4(t2, n + 2, d0, d1, d2, d3, i0, i1, i2, i3);
        bins4(t3, n + 3, d0, d1, d2, d3, i0, i1, i2, i3);
    }
    float power = fmaxf(sp[0], 0.0f) + 1e-6f;
    knn_tail(g, lx, ly, i0, i1, i2, i3, kvpos, attnw, vws, power, head);
}

// ---------------------------------------------------------------------------
// Kernel 4: out = head @ W_out + b_out  (f32 store)
// ---------------------------------------------------------------------------
__global__ void k_out(const float* __restrict__ head, const float* __restrict__ Wout,
                      const float* __restrict__ bout, float* __restrict__ out) {
    int r0 = blockIdx.x * 4;
    __shared__ float hs[4][D];
    for (int t = threadIdx.x; t < 4 * D; t += 256) hs[t >> 8][t & 255] = head[(size_t)r0 * D + t];
    __syncthreads();
    int c = threadIdx.x;
    float a0 = 0.f, a1 = 0.f, a2 = 0.f, a3 = 0.f;
    for (int d = 0; d < D; ++d) {
        float w = Wout[d * D + c];
        a0 = fmaf(hs[0][d], w, a0); a1 = fmaf(hs[1][d], w, a1);
        a2 = fmaf(hs[2][d], w, a2); a3 = fmaf(hs[3][d], w, a3);
    }
    float bias = bout[c];
    out[(size_t)(r0 + 0) * D + c] = a0 + bias;
    out[(size_t)(r0 + 1) * D + c] = a1 + bias;
    out[(size_t)(r0 + 2) * D + c] = a2 + bias;
    out[(size_t)(r0 + 3) * D + c] = a3 + bias;
}

// ---------------------------------------------------------------------------
extern "C" void kernel_launch(void* const* d_in, const int* in_sizes, int n_in,
                              void* d_out, int out_size, void* d_ws, size_t ws_size,
                              hipStream_t stream) {
    (void)in_sizes; (void)n_in; (void)out_size;
    const float* q     = (const float*)d_in[0];
    const float* qpos  = (const float*)d_in[1];
    const float* kv    = (const float*)d_in[2];
    const float* kvp   = (const float*)d_in[3];
    const float* Woff  = (const float*)d_in[4];
    const float* boff  = (const float*)d_in[5];
    const float* Wattn = (const float*)d_in[6];
    const float* battn = (const float*)d_in[7];
    const float* Wv    = (const float*)d_in[8];
    const float* bv    = (const float*)d_in[9];
    const float* Wout  = (const float*)d_in[10];
    const float* bout  = (const float*)d_in[11];
    const float* sp    = (const float*)d_in[12];
    float* out = (float*)d_out;

    char* ws = (char*)d_ws;
    float* loc      = (float*)(ws + OFF_LOC);
    float* attnw    = (float*)(ws + OFF_ATTN);
    float* vws      = (float*)(ws + OFF_VWS);
    float* head     = (float*)(ws + OFF_HEAD);
    float4* pts4    = (float4*)(ws + OFF_PTS);
    int* cellStart  = (int*)(ws + OFF_CST);

    hipLaunchKernelGGL(k_offattn, dim3(BATCH * NQ), dim3(128), 0, stream,
                       q, qpos, Woff, boff, Wattn, battn, loc, attnw);
    hipLaunchKernelGGL(k_values, dim3(BATCH * NKV / 4), dim3(256), 0, stream,
                       kv, Wv, bv, vws);
    if (ws_size >= (size_t)WS_NEED) {
        hipLaunchKernelGGL(k_bin, dim3(BATCH), dim3(256), 0, stream,
                           kvp, pts4, cellStart);
        hipLaunchKernelGGL(k_knn_grid2, dim3(BATCH * H * NQ * K / 64), dim3(256), 0, stream,
                           kvp, loc, attnw, vws, sp, pts4, cellStart, head);
    } else {
        hipLaunchKernelGGL(k_knn_fused, dim3(BATCH * H * NQ * K / 256), dim3(256), 0, stream,
                           kvp, loc, attnw, vws, sp, head);
    }
    hipLaunchKernelGGL(k_out, dim3(BATCH * NQ / 4), dim3(256), 0, stream,
                       head, Wout, bout, out);
}

// Round 9
// 119.506 us; speedup vs baseline: 1.1759x; 1.1759x over previous
//
#include <hip/hip_runtime.h>
#include <math.h>

#define H 8
#define K 4
#define NN 4
#define D 256
#define NQ 1024
#define NKV 2048
#define BATCH 2
#define CH 32           // D / H
#define GC 16           // grid cells per axis
#define CELLH 0.0625f   // 1/16

// workspace layout (bytes)
#define OFF_LOC   0u          // 65536 * float2 = 512 KB
#define OFF_ATTN  524288u     // 65536 * f32    = 256 KB
#define OFF_VWS   786432u     // 16*2048*32 f32 = 4 MB
#define OFF_HEAD  4980736u    // 2*1024*256 f32 = 2 MB
#define OFF_PTS   7077888u    // 2*2048 float4  = 64 KB (cell-sorted)
#define OFF_CST   7143424u    // 2*257 i32 cell starts (+pad)
#define WS_NEED   7147520u

// ---------------------------------------------------------------------------
// Kernel 1: off = q@W_off + b_off (sequential fmaf chain = Eigen/oneDNN sgemm
// semantics, bias after) -> loc; attn = softmax_K(q@W_attn + b_attn)
// ---------------------------------------------------------------------------
__global__ void k_offattn(const float* __restrict__ q, const float* __restrict__ qpos,
                          const float* __restrict__ Woff, const float* __restrict__ boff,
                          const float* __restrict__ Wattn, const float* __restrict__ battn,
                          float* __restrict__ loc, float* __restrict__ attnw) {
    int row = blockIdx.x;            // b*NQ + q
    int b = row >> 10, qi = row & (NQ - 1);
    __shared__ float qs[D];
    for (int d = threadIdx.x; d < D; d += blockDim.x) qs[d] = q[(size_t)row * D + d];
    __syncthreads();
    int j = threadIdx.x;
    if (j < 64) {
        float acc = 0.0f;
        for (int d = 0; d < D; ++d) acc = fmaf(qs[d], Woff[d * 64 + j], acc);
        float off = acc + boff[j];               // bias after, like np
        int xy = j & 1;
        int hk = j >> 1;                         // h*4 + k
        int h = hk >> 2, k = hk & 3;
        float L = qpos[(size_t)row * 2 + xy] + off;
        int g = ((b * H + h) * NQ + qi) * K + k;
        loc[(size_t)g * 2 + xy] = L;
    } else if (j < 96) {
        int j2 = j - 64;                         // h*4 + k
        float acc = 0.0f;
        for (int d = 0; d < D; ++d) acc = fmaf(qs[d], Wattn[d * 32 + j2], acc);
        acc += battn[j2];
        float m = acc;
        m = fmaxf(m, __shfl_xor(m, 1));
        m = fmaxf(m, __shfl_xor(m, 2));
        float e = expf(acc - m);
        float s = e;
        s += __shfl_xor(s, 1);
        s += __shfl_xor(s, 2);
        float w = e / s;
        int h = j2 >> 2, k = j2 & 3;
        attnw[((b * H + h) * NQ + qi) * K + k] = w;
    }
}

// ---------------------------------------------------------------------------
// Kernel 2: values = kv @ W_v + b_v, stored transposed as [b*H][n_kv][32] f32.
// ---------------------------------------------------------------------------
__global__ void k_values(const float* __restrict__ kv, const float* __restrict__ Wv,
                         const float* __restrict__ bv, float* __restrict__ vws) {
    int r0 = blockIdx.x * 4;         // row = b*NKV + n
    __shared__ float ks[4][D];
    for (int t = threadIdx.x; t < 4 * D; t += 256) ks[t >> 8][t & 255] = kv[(size_t)r0 * D + t];
    __syncthreads();
    int c = threadIdx.x;             // h*32 + cc
    float a0 = 0.f, a1 = 0.f, a2 = 0.f, a3 = 0.f;
    for (int d = 0; d < D; ++d) {
        float w = Wv[d * D + c];
        a0 = fmaf(ks[0][d], w, a0); a1 = fmaf(ks[1][d], w, a1);
        a2 = fmaf(ks[2][d], w, a2); a3 = fmaf(ks[3][d], w, a3);
    }
    float bias = bv[c];
    a0 += bias; a1 += bias; a2 += bias; a3 += bias;
    int h = c >> 5, cc = c & 31;
    float va[4] = {a0, a1, a2, a3};
    for (int r = 0; r < 4; ++r) {
        int row = r0 + r;
        int b = row >> 11, n = row & (NKV - 1);
        vws[(((size_t)(b * H + h) * NKV) + n) * CH + cc] = va[r];
    }
}

// ---------------------------------------------------------------------------
// Kernel B: bin kv points into 16x16 cells (per batch), cell-sorted float4
// (-2x, -2y, x^2+y^2, (float)origIdx) + cellStart[257].
// ---------------------------------------------------------------------------
__global__ void k_bin(const float* __restrict__ kvpos, float4* __restrict__ pts4,
                      int* __restrict__ cellStart) {
    #pragma clang fp contract(off)
    int b = blockIdx.x;
    int tid = threadIdx.x;
    __shared__ int cnt[GC * GC];
    __shared__ int ofs[GC * GC + 1];
    __shared__ int cur[GC * GC];
    if (tid < GC * GC) cnt[tid] = 0;
    __syncthreads();
    for (int n = tid; n < NKV; n += 256) {
        float x = kvpos[(size_t)(b * NKV + n) * 2 + 0];
        float y = kvpos[(size_t)(b * NKV + n) * 2 + 1];
        int ix = min(GC - 1, max(0, (int)floorf(x * (float)GC)));
        int iy = min(GC - 1, max(0, (int)floorf(y * (float)GC)));
        atomicAdd(&cnt[iy * GC + ix], 1);
    }
    __syncthreads();
    if (tid == 0) {
        int s = 0;
        for (int c = 0; c < GC * GC; ++c) { ofs[c] = s; s += cnt[c]; }
        ofs[GC * GC] = s;
    }
    __syncthreads();
    for (int t = tid; t < GC * GC + 1; t += 256) cellStart[b * 257 + t] = ofs[t];
    if (tid < GC * GC) cur[tid] = ofs[tid];
    __syncthreads();
    for (int n = tid; n < NKV; n += 256) {
        float x = kvpos[(size_t)(b * NKV + n) * 2 + 0];
        float y = kvpos[(size_t)(b * NKV + n) * 2 + 1];
        int ix = min(GC - 1, max(0, (int)floorf(x * (float)GC)));
        int iy = min(GC - 1, max(0, (int)floorf(y * (float)GC)));
        int pos = atomicAdd(&cur[iy * GC + ix], 1);
        pts4[(size_t)b * NKV + pos] = make_float4(-2.0f * x, -2.0f * y, x * x + y * y, (float)n);
    }
}

// ---------------------------------------------------------------------------
// Branchless lexicographic (d, idx) stable top-4 insert.  Order-independent
// selection; reproduces lax.top_k (smaller d first; ties -> smaller index).
// Plain version: feed sets must be duplicate-free.
// ---------------------------------------------------------------------------
__device__ __forceinline__ void lexins(float t, int n,
                                       float& d0, float& d1, float& d2, float& d3,
                                       int& i0, int& i1, int& i2, int& i3) {
    bool c0 = (t < d0) || (t == d0 && n < i0);
    bool c1 = (t < d1) || (t == d1 && n < i1);
    bool c2 = (t < d2) || (t == d2 && n < i2);
    bool c3 = (t < d3) || (t == d3 && n < i3);
    d3 = c3 ? (c2 ? d2 : t) : d3;   i3 = c3 ? (c2 ? i2 : n) : i3;
    d2 = c2 ? (c1 ? d1 : t) : d2;   i2 = c2 ? (c1 ? i1 : n) : i2;
    d1 = c1 ? (c0 ? d0 : t) : d1;   i1 = c1 ? (c0 ? i0 : n) : i1;
    d0 = c0 ? t : d0;               i0 = c0 ? n : i0;
}

// DEDUP variant: for ring re-merges where lists share phase-1 survivors.
__device__ __forceinline__ void lexins_d(float t, int n,
                                         float& d0, float& d1, float& d2, float& d3,
                                         int& i0, int& i1, int& i2, int& i3) {
    bool nd = !((n == i0) | (n == i1) | (n == i2) | (n == i3));
    bool c0 = nd && ((t < d0) || (t == d0 && n < i0));
    bool c1 = nd && ((t < d1) || (t == d1 && n < i1));
    bool c2 = nd && ((t < d2) || (t == d2 && n < i2));
    bool c3 = nd && ((t < d3) || (t == d3 && n < i3));
    d3 = c3 ? (c2 ? d2 : t) : d3;   i3 = c3 ? (c2 ? i2 : n) : i3;
    d2 = c2 ? (c1 ? d1 : t) : d2;   i2 = c2 ? (c1 ? i1 : n) : i2;
    d1 = c1 ? (c0 ? d0 : t) : d1;   i1 = c1 ? (c0 ? i0 : n) : i1;
    d0 = c0 ? t : d0;               i0 = c0 ? n : i0;
}

// strict-< variant for the ascending-order brute-force fallback
__device__ __forceinline__ void bins4(float t, int n,
                                      float& d0, float& d1, float& d2, float& d3,
                                      int& i0, int& i1, int& i2, int& i3) {
    bool c0 = t < d0, c1 = t < d1, c2 = t < d2, c3 = t < d3;
    d3 = c3 ? (c2 ? d2 : t) : d3;   i3 = c3 ? (c2 ? i2 : n) : i3;
    d2 = c2 ? (c1 ? d1 : t) : d2;   i2 = c2 ? (c1 ? i1 : n) : i2;
    d1 = c1 ? (c0 ? d0 : t) : d1;   i1 = c1 ? (c0 ? i0 : n) : i1;
    d0 = c0 ? t : d0;               i0 = c0 ? n : i0;
}

// ---------------------------------------------------------------------------
// Shepard weights + gather + weighted sum + head write (fallback tail).
// ---------------------------------------------------------------------------
__device__ __forceinline__ void knn_tail(int g, float lx, float ly,
                                         int i0, int i1, int i2, int i3,
                                         const float* __restrict__ kvpos,
                                         const float* __restrict__ attnw,
                                         const float* __restrict__ vws,
                                         float power, float* __restrict__ head) {
    #pragma clang fp contract(off)
    int bh = g >> 12;
    int b = bh >> 3, h = bh & 7;
    int qi = (g >> 2) & (NQ - 1);
    int k = g & 3;
    int idx[4] = {i0, i1, i2, i3};
    float z[4];
    #pragma unroll
    for (int u = 0; u < 4; ++u) {
        float kx = kvpos[(size_t)(b * NKV + idx[u]) * 2 + 0];
        float ky = kvpos[(size_t)(b * NKV + idx[u]) * 2 + 1];
        float dx = kx - lx;
        float dy = ky - ly;
        float dist = sqrtf(dx * dx + dy * dy) + 1e-6f;
        z[u] = -power * dist;
    }
    float m = fmaxf(fmaxf(z[0], z[1]), fmaxf(z[2], z[3]));
    float e0 = expf(z[0] - m), e1 = expf(z[1] - m), e2 = expf(z[2] - m), e3 = expf(z[3] - m);
    float esum = e0 + e1 + e2 + e3;
    float w0 = e0 / esum, w1 = e1 / esum, w2 = e2 / esum, w3 = e3 / esum;

    const float4* vp0 = (const float4*)(vws + ((size_t)bh * NKV + i0) * CH);
    const float4* vp1 = (const float4*)(vws + ((size_t)bh * NKV + i1) * CH);
    const float4* vp2 = (const float4*)(vws + ((size_t)bh * NKV + i2) * CH);
    const float4* vp3 = (const float4*)(vws + ((size_t)bh * NKV + i3) * CH);
    float a = attnw[g];
    float4 acc[8];
    #pragma unroll
    for (int t = 0; t < 8; ++t) {
        float4 x0 = vp0[t], x1 = vp1[t], x2 = vp2[t], x3 = vp3[t];
        float4 r;
        r.x = a * (w0 * x0.x + w1 * x1.x + w2 * x2.x + w3 * x3.x);
        r.y = a * (w0 * x0.y + w1 * x1.y + w2 * x2.y + w3 * x3.y);
        r.z = a * (w0 * x0.z + w1 * x1.z + w2 * x2.z + w3 * x3.z);
        r.w = a * (w0 * x0.w + w1 * x1.w + w2 * x2.w + w3 * x3.w);
        r.x += __shfl_xor(r.x, 1); r.x += __shfl_xor(r.x, 2);
        r.y += __shfl_xor(r.y, 1); r.y += __shfl_xor(r.y, 2);
        r.z += __shfl_xor(r.z, 1); r.z += __shfl_xor(r.z, 2);
        r.w += __shfl_xor(r.w, 1); r.w += __shfl_xor(r.w, 2);
        acc[t] = r;
    }
    float4* hp = (float4*)(head + ((size_t)(b * NQ + qi)) * D + h * CH);
    hp[k * 2]     = acc[k * 2];
    hp[k * 2 + 1] = acc[k * 2 + 1];
}

// ---------------------------------------------------------------------------
// Kernel 3: grid-accelerated exact 4-NN, 8 LANES PER POINT, ILP'd scan.
// Phase-1 flattens the 3x3 box rows into one index range and batch-loads 4
// independent candidates per iteration (restores MLP).  Phase-1 butterfly
// merges use plain lexins (lane candidate sets disjoint at every step);
// rare ring re-merges use dedup lexins_d.  t formula bitwise-identical.
// 2048 blocks -> 8 blocks/CU -> 32 waves/CU.
// ---------------------------------------------------------------------------
__global__ void k_knn_grid2(const float* __restrict__ kvpos, const float* __restrict__ loc,
                            const float* __restrict__ attnw, const float* __restrict__ vws,
                            const float* __restrict__ sp,
                            const float4* __restrict__ pts4, const int* __restrict__ cellStart,
                            float* __restrict__ head) {
    #pragma clang fp contract(off)
    int lane = threadIdx.x;
    int s = lane & 7;
    int g = blockIdx.x * 32 + (lane >> 3);    // point id
    int b = g >> 15;
    int bh = g >> 12;

    __shared__ int cst[GC * GC + 1];
    for (int i = threadIdx.x; i < GC * GC + 1; i += 256) cst[i] = cellStart[b * 257 + i];
    __syncthreads();

    const float4* gp = pts4 + (size_t)b * NKV;

    const float2* lp = (const float2*)loc;
    float2 L = lp[g];
    float lx = L.x, ly = L.y;
    float sl = lx * lx + ly * ly;

    int ix = min(GC - 1, max(0, (int)floorf(lx * (float)GC)));
    int iy = min(GC - 1, max(0, (int)floorf(ly * (float)GC)));

    float d0 = 1e30f, d1 = 1e30f, d2 = 1e30f, d3 = 1e30f;
    int i0 = 0x7FFFFFFF, i1 = 0x7FFFFFFF, i2 = 0x7FFFFFFF, i3 = 0x7FFFFFFF;

#define INS1(P) { float tt = (sl + (P).z) + fmaf(ly, (P).y, lx * (P).x);      \
                  lexins(tt, (int)(P).w, d0, d1, d2, d3, i0, i1, i2, i3); }

    // ---- phase 1: clamped 3x3 box, flattened rows, 4-wide batched loads ----
    {
        int bx0 = max(ix - 1, 0), bx1 = min(ix + 1, GC - 1);
        int by0 = max(iy - 1, 0), by1 = min(iy + 1, GC - 1);
        int a0 = cst[by0 * GC + bx0];
        int l0 = cst[by0 * GC + bx1 + 1] - a0;
        int a1 = 0, l1 = 0, a2 = 0, l2 = 0;
        if (by0 + 1 <= by1) { a1 = cst[(by0 + 1) * GC + bx0]; l1 = cst[(by0 + 1) * GC + bx1 + 1] - a1; }
        if (by0 + 2 <= by1) { a2 = cst[(by0 + 2) * GC + bx0]; l2 = cst[(by0 + 2) * GC + bx1 + 1] - a2; }
        int l01 = l0 + l1;
        int m = l01 + l2;
        int f = s;
        for (; f + 24 < m; f += 32) {
            int f0 = f, f1 = f + 8, f2 = f + 16, f3 = f + 24;
            int j0 = f0 < l0 ? a0 + f0 : (f0 < l01 ? a1 + (f0 - l0) : a2 + (f0 - l01));
            int j1 = f1 < l0 ? a0 + f1 : (f1 < l01 ? a1 + (f1 - l0) : a2 + (f1 - l01));
            int j2 = f2 < l0 ? a0 + f2 : (f2 < l01 ? a1 + (f2 - l0) : a2 + (f2 - l01));
            int j3 = f3 < l0 ? a0 + f3 : (f3 < l01 ? a1 + (f3 - l0) : a2 + (f3 - l01));
            float4 p0 = gp[j0], p1 = gp[j1], p2 = gp[j2], p3 = gp[j3];
            INS1(p0); INS1(p1); INS1(p2); INS1(p3);
        }
        for (; f < m; f += 8) {
            int j = f < l0 ? a0 + f : (f < l01 ? a1 + (f - l0) : a2 + (f - l01));
            float4 p = gp[j];
            INS1(p);
        }
    }

#define MERGE_P(M) {                                                           \
        float e0 = __shfl_xor(d0, M), e1 = __shfl_xor(d1, M);                  \
        float e2 = __shfl_xor(d2, M), e3 = __shfl_xor(d3, M);                  \
        int j0 = __shfl_xor(i0, M), j1 = __shfl_xor(i1, M);                    \
        int j2 = __shfl_xor(i2, M), j3 = __shfl_xor(i3, M);                    \
        lexins(e0, j0, d0, d1, d2, d3, i0, i1, i2, i3);                        \
        lexins(e1, j1, d0, d1, d2, d3, i0, i1, i2, i3);                        \
        lexins(e2, j2, d0, d1, d2, d3, i0, i1, i2, i3);                        \
        lexins(e3, j3, d0, d1, d2, d3, i0, i1, i2, i3);                        \
    }
#define MERGE_D(M) {                                                           \
        float e0 = __shfl_xor(d0, M), e1 = __shfl_xor(d1, M);                  \
        float e2 = __shfl_xor(d2, M), e3 = __shfl_xor(d3, M);                  \
        int j0 = __shfl_xor(i0, M), j1 = __shfl_xor(i1, M);                    \
        int j2 = __shfl_xor(i2, M), j3 = __shfl_xor(i3, M);                    \
        lexins_d(e0, j0, d0, d1, d2, d3, i0, i1, i2, i3);                      \
        lexins_d(e1, j1, d0, d1, d2, d3, i0, i1, i2, i3);                      \
        lexins_d(e2, j2, d0, d1, d2, d3, i0, i1, i2, i3);                      \
        lexins_d(e3, j3, d0, d1, d2, d3, i0, i1, i2, i3);                      \
    }

    MERGE_P(1);
    MERGE_P(2);
    MERGE_P(4);

    // done check for box radius r (post-merge: uniform across the 8-lane group)
    auto done_at = [&](int r) -> bool {
        int bx0 = ix - r, bx1 = ix + r, by0 = iy - r, by1 = iy + r;
        float bound = 1e30f;
        if (bx0 > 0)      bound = fminf(bound, lx - (float)bx0 * CELLH);
        if (bx1 < GC - 1) bound = fminf(bound, (float)(bx1 + 1) * CELLH - lx);
        if (by0 > 0)      bound = fminf(bound, ly - (float)by0 * CELLH);
        if (by1 < GC - 1) bound = fminf(bound, (float)(by1 + 1) * CELLH - ly);
        bool covered = (bx0 <= 0 && bx1 >= GC - 1 && by0 <= 0 && by1 >= GC - 1);
        return covered || (d3 < bound * bound - 1e-5f);
    };

#define SCAN_RANGE_S(JLO, JHI)                                       \
    for (int j = (JLO) + s; j < (JHI); j += 8) {                     \
        float4 p = gp[j];                                            \
        INS1(p);                                                     \
    }

    int r = 1;
    bool need = !done_at(1);
    while (__any(need)) {
        ++r;
        if (need) {
            int ry0 = iy - r, ry1 = iy + r;
            int rx0 = ix - r, rx1 = ix + r;
            int ca = max(rx0, 0), cb = min(rx1, GC - 1);
            if (ry0 >= 0)      { int base = ry0 * GC; SCAN_RANGE_S(cst[base + ca], cst[base + cb + 1]); }
            if (ry1 <= GC - 1) { int base = ry1 * GC; SCAN_RANGE_S(cst[base + ca], cst[base + cb + 1]); }
            int ya = max(ry0 + 1, 0), yb = min(ry1 - 1, GC - 1);
            if (rx0 >= 0)      for (int cy = ya; cy <= yb; ++cy) { int c = cy * GC + rx0; SCAN_RANGE_S(cst[c], cst[c + 1]); }
            if (rx1 <= GC - 1) for (int cy = ya; cy <= yb; ++cy) { int c = cy * GC + rx1; SCAN_RANGE_S(cst[c], cst[c + 1]); }
            MERGE_D(1);
            MERGE_D(2);
            MERGE_D(4);
            need = !done_at(r);
        }
    }
#undef SCAN_RANGE_S
#undef MERGE_P
#undef MERGE_D
#undef INS1

    // ---- tail, split 8-way over channel chunks (t = s) ----
    int bb = bh >> 3, h = bh & 7;
    int qi = (g >> 2) & (NQ - 1);
    float power = fmaxf(sp[0], 0.0f) + 1e-6f;
    int idx[4] = {i0, i1, i2, i3};
    float z[4];
    #pragma unroll
    for (int u = 0; u < 4; ++u) {
        float kx = kvpos[(size_t)(bb * NKV + idx[u]) * 2 + 0];
        float ky = kvpos[(size_t)(bb * NKV + idx[u]) * 2 + 1];
        float dx = kx - lx;
        float dy = ky - ly;
        float dist = sqrtf(dx * dx + dy * dy) + 1e-6f;
        z[u] = -power * dist;
    }
    float m = fmaxf(fmaxf(z[0], z[1]), fmaxf(z[2], z[3]));
    float e0 = expf(z[0] - m), e1 = expf(z[1] - m), e2 = expf(z[2] - m), e3 = expf(z[3] - m);
    float esum = e0 + e1 + e2 + e3;
    float w0 = e0 / esum, w1 = e1 / esum, w2 = e2 / esum, w3 = e3 / esum;

    const float4* vp0 = (const float4*)(vws + ((size_t)bh * NKV + i0) * CH);
    const float4* vp1 = (const float4*)(vws + ((size_t)bh * NKV + i1) * CH);
    const float4* vp2 = (const float4*)(vws + ((size_t)bh * NKV + i2) * CH);
    const float4* vp3 = (const float4*)(vws + ((size_t)bh * NKV + i3) * CH);
    float a = attnw[g];
    float4* hp = (float4*)(head + ((size_t)(bb * NQ + qi)) * D + h * CH);
    {
        float4 x0 = vp0[s], x1 = vp1[s], x2 = vp2[s], x3 = vp3[s];
        float4 rr;
        rr.x = a * (w0 * x0.x + w1 * x1.x + w2 * x2.x + w3 * x3.x);
        rr.y = a * (w0 * x0.y + w1 * x1.y + w2 * x2.y + w3 * x3.y);
        rr.z = a * (w0 * x0.z + w1 * x1.z + w2 * x2.z + w3 * x3.z);
        rr.w = a * (w0 * x0.w + w1 * x1.w + w2 * x2.w + w3 * x3.w);
        rr.x += __shfl_xor(rr.x, 8); rr.x += __shfl_xor(rr.x, 16);  // sum over k
        rr.y += __shfl_xor(rr.y, 8); rr.y += __shfl_xor(rr.y, 16);
        rr.z += __shfl_xor(rr.z, 8); rr.z += __shfl_xor(rr.z, 16);
        rr.w += __shfl_xor(rr.w, 8); rr.w += __shfl_xor(rr.w, 16);
        if (((lane >> 3) & 3) == 0) hp[s] = rr;                     // k==0 lanes write
    }
}

// Fallback (ws too small): brute-force fused scan (round-4 validated path)
__global__ void k_knn_fused(const float* __restrict__ kvpos, const float* __restrict__ loc,
                            const float* __restrict__ attnw, const float* __restrict__ vws,
                            const float* __restrict__ sp, float* __restrict__ head) {
    #pragma clang fp contract(off)
    int g = blockIdx.x * 256 + threadIdx.x;
    int bh = g >> 12;
    int b = bh >> 3;
    __shared__ float sx[NKV];
    __shared__ float sy[NKV];
    __shared__ float sz[NKV];
    for (int n = threadIdx.x; n < NKV; n += 256) {
        float x = kvpos[(size_t)(b * NKV + n) * 2 + 0];
        float y = kvpos[(size_t)(b * NKV + n) * 2 + 1];
        sx[n] = -2.0f * x;
        sy[n] = -2.0f * y;
        sz[n] = x * x + y * y;
    }
    __syncthreads();
    const float2* lp = (const float2*)loc;
    float2 L = lp[g];
    float lx = L.x, ly = L.y;
    float sl = lx * lx + ly * ly;
    const float4* x4 = (const float4*)sx;
    const float4* y4 = (const float4*)sy;
    const float4* z4 = (const float4*)sz;
    float d0 = 1e30f, d1 = 1e30f, d2 = 1e30f, d3 = 1e30f;
    int i0 = 0, i1 = 0, i2 = 0, i3 = 0;
    for (int n = 0; n < NKV; n += 4) {
        int v = n >> 2;
        float4 xA = x4[v], yA = y4[v], zA = z4[v];
        float t0 = (sl + zA.x) + fmaf(ly, yA.x, lx * xA.x);
        float t1 = (sl + zA.y) + fmaf(ly, yA.y, lx * xA.y);
        float t2 = (sl + zA.z) + fmaf(ly, yA.z, lx * xA.z);
        float t3 = (sl + zA.w) + fmaf(ly, yA.w, lx * xA.w);
        bins4(t0, n + 0, d0, d1, d2, d3, i0, i1, i2, i3);
        bins4(t1, n + 1, d0, d1, d2, d3, i0, i1, i2, i3);
        bins4(t2, n + 2, d0, d1, d2, d3, i0, i1, i2, i3);
        bins4(t3, n + 3, d0, d1, d2, d3, i0, i1, i2, i3);
    }
    float power = fmaxf(sp[0], 0.0f) + 1e-6f;
    knn_tail(g, lx, ly, i0, i1, i2, i3, kvpos, attnw, vws, power, head);
}

// ---------------------------------------------------------------------------
// Kernel 4: out = head @ W_out + b_out  (f32 store)
// ---------------------------------------------------------------------------
__global__ void k_out(const float* __restrict__ head, const float* __restrict__ Wout,
                      const float* __restrict__ bout, float* __restrict__ out) {
    int r0 = blockIdx.x * 4;
    __shared__ float hs[4][D];
    for (int t = threadIdx.x; t < 4 * D; t += 256) hs[t >> 8][t & 255] = head[(size_t)r0 * D + t];
    __syncthreads();
    int c = threadIdx.x;
    float a0 = 0.f, a1 = 0.f, a2 = 0.f, a3 = 0.f;
    for (int d = 0; d < D; ++d) {
        float w = Wout[d * D + c];
        a0 = fmaf(hs[0][d], w, a0); a1 = fmaf(hs[1][d], w, a1);
        a2 = fmaf(hs[2][d], w, a2); a3 = fmaf(hs[3][d], w, a3);
    }
    float bias = bout[c];
    out[(size_t)(r0 + 0) * D + c] = a0 + bias;
    out[(size_t)(r0 + 1) * D + c] = a1 + bias;
    out[(size_t)(r0 + 2) * D + c] = a2 + bias;
    out[(size_t)(r0 + 3) * D + c] = a3 + bias;
}

// ---------------------------------------------------------------------------
extern "C" void kernel_launch(void* const* d_in, const int* in_sizes, int n_in,
                              void* d_out, int out_size, void* d_ws, size_t ws_size,
                              hipStream_t stream) {
    (void)in_sizes; (void)n_in; (void)out_size;
    const float* q     = (const float*)d_in[0];
    const float* qpos  = (const float*)d_in[1];
    const float* kv    = (const float*)d_in[2];
    const float* kvp   = (const float*)d_in[3];
    const float* Woff  = (const float*)d_in[4];
    const float* boff  = (const float*)d_in[5];
    const float* Wattn = (const float*)d_in[6];
    const float* battn = (const float*)d_in[7];
    const float* Wv    = (const float*)d_in[8];
    const float* bv    = (const float*)d_in[9];
    const float* Wout  = (const float*)d_in[10];
    const float* bout  = (const float*)d_in[11];
    const float* sp    = (const float*)d_in[12];
    float* out = (float*)d_out;

    char* ws = (char*)d_ws;
    float* loc      = (float*)(ws + OFF_LOC);
    float* attnw    = (float*)(ws + OFF_ATTN);
    float* vws      = (float*)(ws + OFF_VWS);
    float* head     = (float*)(ws + OFF_HEAD);
    float4* pts4    = (float4*)(ws + OFF_PTS);
    int* cellStart  = (int*)(ws + OFF_CST);

    hipLaunchKernelGGL(k_offattn, dim3(BATCH * NQ), dim3(128), 0, stream,
                       q, qpos, Woff, boff, Wattn, battn, loc, attnw);
    hipLaunchKernelGGL(k_values, dim3(BATCH * NKV / 4), dim3(256), 0, stream,
                       kv, Wv, bv, vws);
    if (ws_size >= (size_t)WS_NEED) {
        hipLaunchKernelGGL(k_bin, dim3(BATCH), dim3(256), 0, stream,
                           kvp, pts4, cellStart);
        hipLaunchKernelGGL(k_knn_grid2, dim3(BATCH * H * NQ * K / 32), dim3(256), 0, stream,
                           kvp, loc, attnw, vws, sp, pts4, cellStart, head);
    } else {
        hipLaunchKernelGGL(k_knn_fused, dim3(BATCH * H * NQ * K / 256), dim3(256), 0, stream,
                           kvp, loc, attnw, vws, sp, head);
    }
    hipLaunchKernelGGL(k_out, dim3(BATCH * NQ / 4), dim3(256), 0, stream,
                       head, Wout, bout, out);
}